// Round 11
// baseline (873.977 us; speedup 1.0000x reference)
//
#include <hip/hip_runtime.h>
#include <cstdint>
#include <cstddef>

#define D 2048
#define L 8
#define KS 2048            // state/B k-extent (signed state)
#define BM 256
#define BN 128
#define BK 64
#define NT (KS / BK)       // 32 K-tiles
#define BROWS 256          // staged B rows: 128 sum + 128 dif
#define BUFSZ (BROWS * BK) // 16384 f16 = 32 KiB per LDS buffer (B only)

typedef _Float16 f16;
typedef _Float16 f16x4 __attribute__((ext_vector_type(4)));
typedef _Float16 f16x8 __attribute__((ext_vector_type(8)));
typedef float f32x4 __attribute__((ext_vector_type(4)));
typedef unsigned int u32x4 __attribute__((ext_vector_type(4)));

__device__ __forceinline__ void gload16(const void* g, void* l) {
  __builtin_amdgcn_global_load_lds(
      (const __attribute__((address_space(1))) void*)g,
      (__attribute__((address_space(3))) void*)l, 16, 0, 0);
}

// ---- init: signed A into both chains, bias init + step-0 contribution ------
__global__ __launch_bounds__(256) void k_init(
    const float* __restrict__ A, const float* __restrict__ b,
    const float* __restrict__ db1, const float* __restrict__ db2,  // layer 7
    f16* __restrict__ Ab, float* __restrict__ blbu, float* __restrict__ outacc) {
  const int m = blockIdx.x, tid = threadIdx.x;
  if (m < 2) {
    f32x4 z = {0.f, 0.f, 0.f, 0.f};
    *(f32x4*)(outacc + m * 2048 + tid * 8) = z;
    *(f32x4*)(outacc + m * 2048 + tid * 8 + 4) = z;
  }
  const int k = tid * 8;
  size_t i = (size_t)m * D + k;
  f32x4 a0 = *(const f32x4*)(A + i);
  f32x4 a1 = *(const f32x4*)(A + i + 4);
  f16x8 h;
  float cL = 0.f, cU = 0.f;
#pragma unroll
  for (int j = 0; j < 8; ++j) {
    float v = (j < 4) ? a0[j] : a1[j - 4];
    h[j] = (f16)v;
    float pf = fmaxf(v, 0.f), nf = fminf(v, 0.f);
    float w1 = db1[k + j], w2 = db2[k + j];
    cL += pf * w1 + nf * w2;
    cU += pf * w2 + nf * w1;
  }
  *(f16x8*)(Ab + (size_t)m * KS + k) = h;
  *(f16x8*)(Ab + (size_t)(D + m) * KS + k) = h;

  __shared__ float redL[4], redU[4];
#pragma unroll
  for (int off = 32; off > 0; off >>= 1) {
    cL += __shfl_down(cL, off);
    cU += __shfl_down(cU, off);
  }
  const int wave = tid >> 6, lane = tid & 63;
  if (lane == 0) { redL[wave] = cL; redU[wave] = cU; }
  __syncthreads();
  if (tid == 0) {
    float bL = b[m] + redL[0] + redL[1] + redL[2] + redL[3];
    float bU = b[m] + redU[0] + redU[1] + redU[2] + redU[3];
    blbu[m] = bL; blbu[D + m] = bU;
  }
}

// ---- standalone prep: Bsum/Bdif transposed panels (layer 7 bootstrap) ------
__global__ __launch_bounds__(512) void k_prep(
    const float* __restrict__ srcAl, const float* __restrict__ srcAu,
    f16* __restrict__ Bb) {
  const int p = blockIdx.x, tid = threadIdx.x;
  const size_t MS = (size_t)D * D;
  const int col = (p & 31) * 64 + (tid & 63);
  const int k0 = (p >> 5) * 64 + (tid >> 6) * 8;
  float sl[8], su[8];
#pragma unroll
  for (int j = 0; j < 8; ++j) {
    sl[j] = srcAl[(size_t)(k0 + j) * D + col];
    su[j] = srcAu[(size_t)(k0 + j) * D + col];
  }
  f16x8 hs, hd;
#pragma unroll
  for (int j = 0; j < 8; ++j) {
    hs[j] = (f16)((sl[j] + su[j]) * 0.5f);
    hd[j] = (f16)((sl[j] - su[j]) * 0.5f);
  }
  *(f16x8*)(Bb + (size_t)col * KS + k0) = hs;
  *(f16x8*)(Bb + MS + (size_t)col * KS + k0) = hd;
}

// ---- step GEMM: C = S·Bsum ± |S|·Bdif --------------------------------------
// 8 waves, per-wave 64x64, BK=64 -> 64 MFMA/wave/barrier, 32 barriers.
// A fragments loaded DIRECTLY global->reg (L2/L3-resident, 1-tile prefetch,
// explicit ping-pong). B (sum+dif) via gload_lds into 96 KiB tri-buffer with
// R2's measured-conflict-free XOR swizzle. Counted vmcnt(12)/(28)/(8).
__global__ __launch_bounds__(512, 2) void k_gemm(
    const f16* __restrict__ A,     // [2D][KS] signed state
    const f16* __restrict__ Bb,    // [2][D][KS] Bsum,Bdif (transposed)
    f16* __restrict__ BTn,         // next layer's B buffer
    const float* __restrict__ nAl, const float* __restrict__ nAu,
    const float* __restrict__ w1, const float* __restrict__ w2,
    float* __restrict__ bdst,      // blbu (t<7) or outacc (t=7)
    f16* __restrict__ An,          // [2D][KS] next state
    const int do_tr, const int wstate) {
  __shared__ __align__(16) f16 lds[3 * BUFSZ];   // 96 KiB tri-buffer (B only)
  const size_t MS = (size_t)D * D;

  // bijective XCD swizzle over the 16x16 tile grid
  const int flat = blockIdx.x;
  const int xcd = flat & 7, idx = flat >> 3;
  const int by = (xcd >> 1) * 4 + (idx >> 3);
  const int bx = (xcd & 1) * 8 + (idx & 7);
  const int m0 = by * BM;
  const int n0 = bx * BN;

  const int tid = threadIdx.x;
  const int wave = tid >> 6, lane = tid & 63;
  const int wm = (wave & 3) * 64, wn = (wave >> 2) * 64;
  const int lr = lane & 15, lq = lane >> 4;
  const int sub = lane >> 3;                 // staging row within 8-row region
  const int cg = ((lane & 7) ^ sub) * 8;     // inverse-swizzled src chunk
  const int low = (m0 < D) ? 1 : 0;
  const unsigned amask = low ? 0x7FFF7FFFu : 0xFFFFFFFFu;  // |S| or -|S|
  const unsigned omask = low ? 0x00000000u : 0x80008000u;
  const f16* Bs = Bb;
  const f16* Bd = Bb + MS;

  f32x4 acc[4][4];
#pragma unroll
  for (int m = 0; m < 4; ++m)
#pragma unroll
    for (int n = 0; n < 4; ++n)
      acc[m][n] = (f32x4){0.f, 0.f, 0.f, 0.f};

  // stage one B K-tile: 4 gload16/thread (32 regions x 8 rows, 128-B rows)
  auto stageB = [&](int kt, int buf) {
    f16* bB = lds + buf * BUFSZ;
    const size_t gk = (size_t)kt * BK;
#pragma unroll
    for (int i = 0; i < 4; ++i) {
      const int r = i * 8 + wave;            // 0..31; r<16 = sum, else dif
      const int row = r * 8 + sub;           // 0..255
      const f16* src = (r < 16) ? (Bs + (size_t)(n0 + row) * KS)
                                : (Bd + (size_t)(n0 + row - 128) * KS);
      gload16(src + gk + cg, bB + r * 512);
    }
  };

  // A fragments for one K-tile, direct global->reg (8 x dwordx4 per lane)
  auto loadA = [&](int kt, f16x8 (&a)[2][4]) {
    const size_t gk = (size_t)kt * BK;
#pragma unroll
    for (int kb = 0; kb < 2; ++kb)
#pragma unroll
      for (int m = 0; m < 4; ++m)
        a[kb][m] = *(const f16x8*)(A + (size_t)(m0 + wm + m * 16 + lr) * KS
                                   + gk + kb * 32 + lq * 8);
  };

  auto compute = [&](const f16* bB, f16x8 (&a)[2][4]) {
#pragma unroll
    for (int kb = 0; kb < 2; ++kb) {
      f16x8 bs4[4], bd4[4];
#pragma unroll
      for (int n = 0; n < 4; ++n) {
        const int row = wn + n * 16 + lr;
        const int ch = ((kb * 4 + lq) ^ (lr & 7)) * 8;   // swizzled chunk
        bs4[n] = *(const f16x8*)(bB + row * BK + ch);
        bd4[n] = *(const f16x8*)(bB + (128 + row) * BK + ch);
      }
      __builtin_amdgcn_s_setprio(1);
#pragma unroll
      for (int m = 0; m < 4; ++m) {
        u32x4 u = *(const u32x4*)&a[kb][m];
        u = (u & amask) | omask;                          // |S| / -|S|
        f16x8 axm = *(const f16x8*)&u;
#pragma unroll
        for (int n = 0; n < 4; ++n) {
          acc[m][n] = __builtin_amdgcn_mfma_f32_16x16x32_f16(
              bs4[n], a[kb][m], acc[m][n], 0, 0, 0);
          acc[m][n] = __builtin_amdgcn_mfma_f32_16x16x32_f16(
              bd4[n], axm, acc[m][n], 0, 0, 0);
        }
      }
      __builtin_amdgcn_s_setprio(0);
    }
  };

  float trl[8], tru[8];   // in-flight transpose column (static indexing)

  auto body = [&](int t, f16x8 (&aCur)[2][4], f16x8 (&aNxt)[2][4]) {
    const f16* bB = lds + (t % 3) * BUFSZ;
    const int tmod = t & 7;
    if (do_tr && tmod == 6) {    // store panel loaded at t-4 (drained)
      const int p = flat * 4 + (t >> 3);
      const int col = (p & 31) * 64 + (tid & 63);
      const int k0 = (p >> 5) * 64 + (tid >> 6) * 8;
      f16x8 hs, hd;
#pragma unroll
      for (int j = 0; j < 8; ++j) {
        hs[j] = (f16)((trl[j] + tru[j]) * 0.5f);
        hd[j] = (f16)((trl[j] - tru[j]) * 0.5f);
      }
      *(f16x8*)(BTn + (size_t)col * KS + k0) = hs;
      *(f16x8*)(BTn + MS + (size_t)col * KS + k0) = hd;
    }
    if (do_tr && tmod == 2) {    // issue 16 f32 column loads for panel
      const int p = flat * 4 + (t >> 3);
      const int col = (p & 31) * 64 + (tid & 63);
      const int k0 = (p >> 5) * 64 + (tid >> 6) * 8;
#pragma unroll
      for (int j = 0; j < 8; ++j) {
        trl[j] = nAl[(size_t)(k0 + j) * D + col];
        tru[j] = nAu[(size_t)(k0 + j) * D + col];
      }
    }
    __builtin_amdgcn_sched_barrier(0);   // pin VMEM issue order
    if (t + 1 < NT) loadA(t + 1, aNxt);
    if (t + 2 < NT) stageB(t + 2, (t + 2) % 3);
    compute(bB, aCur);
    if (t + 2 < NT) {
      if (do_tr && tmod == 2)
        asm volatile("s_waitcnt vmcnt(28)" ::: "memory");  // +16 tr in flight
      else
        asm volatile("s_waitcnt vmcnt(12)" ::: "memory");  // A8+B4 in flight
    } else if (t + 1 < NT) {
      asm volatile("s_waitcnt vmcnt(8)" ::: "memory");     // A8 in flight
    }
    __builtin_amdgcn_sched_barrier(0);
    __builtin_amdgcn_s_barrier();
    __builtin_amdgcn_sched_barrier(0);
  };

  // prologue: A(0) to regs; B(0),B(1) staged; wait A(0)+B(0)
  f16x8 aA[2][4], aB[2][4];
  loadA(0, aA);
  stageB(0, 0);
  stageB(1, 1);
  asm volatile("s_waitcnt vmcnt(4)" ::: "memory");
  __builtin_amdgcn_sched_barrier(0);
  __builtin_amdgcn_s_barrier();
  __builtin_amdgcn_sched_barrier(0);

  for (int tt = 0; tt < NT; tt += 2) {   // explicit 2x unroll: reg ping-pong
    body(tt, aA, aB);
    body(tt + 1, aB, aA);
  }

  // ---- epilogue: signed state store + fused bias contribution ----
  f32x4 w1v[4], w2v[4];
#pragma unroll
  for (int n = 0; n < 4; ++n) {
    const int col = n0 + wn + n * 16 + lq * 4;
    w1v[n] = *(const f32x4*)(w1 + col);
    w2v[n] = *(const f32x4*)(w2 + col);
  }
  float rowsum[4] = {0.f, 0.f, 0.f, 0.f};
#pragma unroll
  for (int m = 0; m < 4; ++m) {
#pragma unroll
    for (int n = 0; n < 4; ++n) {
      const size_t row = (size_t)(m0 + wm + m * 16 + lr);
      const int col = n0 + wn + n * 16 + lq * 4;
      f16x4 h;
#pragma unroll
      for (int r = 0; r < 4; ++r) {
        float v = acc[m][n][r];
        float pf = fmaxf(v, 0.f), qf = fminf(v, 0.f);
        h[r] = (f16)v;
        float wa = low ? w1v[n][r] : w2v[n][r];
        float wb = low ? w2v[n][r] : w1v[n][r];
        rowsum[m] += pf * wa + qf * wb;
      }
      if (wstate)
        *(f16x4*)(An + row * KS + col) = h;
    }
  }
#pragma unroll
  for (int m = 0; m < 4; ++m) {
    float v = rowsum[m];
    v += __shfl_down(v, 32);
    v += __shfl_down(v, 16);
    if (lane < 16)
      atomicAdd(bdst + m0 + wm + m * 16 + lane, v);
  }
}

// ---- final: out[R] = outacc[R] + blbu[R] -----------------------------------
__global__ __launch_bounds__(256) void k_final(
    const float* __restrict__ outacc, const float* __restrict__ blbu,
    float* __restrict__ out) {
  const int R = blockIdx.x * 256 + threadIdx.x;
  out[R] = outacc[R] + blbu[R];
}

// ---- host ------------------------------------------------------------------
extern "C" void kernel_launch(void* const* d_in, const int* in_sizes, int n_in,
                              void* d_out, int out_size, void* d_ws, size_t ws_size,
                              hipStream_t stream) {
  (void)in_sizes; (void)n_in; (void)out_size;
  const float* A   = (const float*)d_in[0];
  const float* b   = (const float*)d_in[1];
  const float* hAl = (const float*)d_in[2];
  const float* hAu = (const float*)d_in[3];
  const float* hbl = (const float*)d_in[4];
  const float* hbu = (const float*)d_in[5];
  const float* lo  = (const float*)d_in[6];
  const float* up  = (const float*)d_in[7];
  float* out = (float*)d_out;

  const size_t AS = (size_t)2 * D * KS;     // signed state elems (f16)
  const size_t BS = (size_t)2 * D * D;      // Bsum+Bdif elems (f16)
  const size_t MS = (size_t)D * D;
  char* base = (char*)d_ws;
  f16* Ab0   = (f16*)base;
  f16* Ab1   = Ab0 + AS;
  f16* Bb0   = Ab1 + AS;
  float* blbu   = (float*)(Bb0 + BS);
  float* outacc = blbu + 2 * D;
  f16* Bb1   = (f16*)(outacc + 2 * D);
  const size_t need_fused = (size_t)((char*)(Bb1 + BS) - base);
  const bool fused = ws_size >= need_fused;

  k_init<<<dim3(D), 256, 0, stream>>>(
      A, b, hbl + (size_t)7 * D, hbu + (size_t)7 * D, Ab0, blbu, outacc);
  k_prep<<<dim3(1024), 512, 0, stream>>>(          // layer 7 -> Bb0
      hAl + (size_t)7 * MS, hAu + (size_t)7 * MS, Bb0);

  f16* cur = Ab0;
  f16* nxt = Ab1;
  for (int t = 0; t < L; ++t) {
    const int nlayer = 6 - t;   // layer for step t+1 (bias weights + transpose)
    const float* w1 = (t < 7) ? hbl + (size_t)nlayer * D : lo;
    const float* w2 = (t < 7) ? hbu + (size_t)nlayer * D : up;
    float* bd = (t < 7) ? blbu : outacc;
    f16* BT  = (fused && (t & 1)) ? Bb1 : Bb0;
    f16* BTn = fused ? ((t & 1) ? Bb0 : Bb1) : Bb0;
    const float* nl = (t < 7) ? hAl + (size_t)nlayer * MS : hAl;
    const float* nu = (t < 7) ? hAu + (size_t)nlayer * MS : hAu;
    if (!fused && t > 0)
      k_prep<<<dim3(1024), 512, 0, stream>>>(
          hAl + (size_t)(7 - t) * MS, hAu + (size_t)(7 - t) * MS, Bb0);
    const int do_tr = (fused && t < 7) ? 1 : 0;
    const int wstate = (t < 7) ? 1 : 0;
    k_gemm<<<dim3(256), 512, 0, stream>>>(cur, BT, BTn, nl, nu, w1, w2, bd,
                                          nxt, do_tr, wstate);
    f16* tmp = cur; cur = nxt; nxt = tmp;
  }
  k_final<<<dim3(2 * D / 256), 256, 0, stream>>>(outacc, blbu, out);
}

// Round 12
// 617.028 us; speedup vs baseline: 1.4164x; 1.4164x over previous
//
#include <hip/hip_runtime.h>
#include <cstdint>
#include <cstddef>

#define D 2048
#define L 8
#define KS 2048            // state/B k-extent (signed state)
#define BM 256
#define BN 128
#define BK 64
#define NT (KS / BK)       // 32 K-tiles
#define AROWS 256          // staged A rows
#define BROWS 256          // staged B rows: 128 sum + 128 dif
#define BUFSZ ((AROWS + BROWS) * BK)   // 32768 f16 = 64 KiB per buffer

typedef _Float16 f16;
typedef _Float16 f16x4 __attribute__((ext_vector_type(4)));
typedef _Float16 f16x8 __attribute__((ext_vector_type(8)));
typedef float f32x4 __attribute__((ext_vector_type(4)));
typedef unsigned int u32x4 __attribute__((ext_vector_type(4)));

__device__ __forceinline__ void gload16(const void* g, void* l) {
  __builtin_amdgcn_global_load_lds(
      (const __attribute__((address_space(1))) void*)g,
      (__attribute__((address_space(3))) void*)l, 16, 0, 0);
}

// ---- init: signed A into both chains, bias init + step-0 contribution ------
__global__ __launch_bounds__(256) void k_init(
    const float* __restrict__ A, const float* __restrict__ b,
    const float* __restrict__ db1, const float* __restrict__ db2,  // layer 7
    f16* __restrict__ Ab, float* __restrict__ blbu, float* __restrict__ outacc) {
  const int m = blockIdx.x, tid = threadIdx.x;
  if (m < 2) {
    f32x4 z = {0.f, 0.f, 0.f, 0.f};
    *(f32x4*)(outacc + m * 2048 + tid * 8) = z;
    *(f32x4*)(outacc + m * 2048 + tid * 8 + 4) = z;
  }
  const int k = tid * 8;
  size_t i = (size_t)m * D + k;
  f32x4 a0 = *(const f32x4*)(A + i);
  f32x4 a1 = *(const f32x4*)(A + i + 4);
  f16x8 h;
  float cL = 0.f, cU = 0.f;
#pragma unroll
  for (int j = 0; j < 8; ++j) {
    float v = (j < 4) ? a0[j] : a1[j - 4];
    h[j] = (f16)v;
    float pf = fmaxf(v, 0.f), nf = fminf(v, 0.f);
    float w1 = db1[k + j], w2 = db2[k + j];
    cL += pf * w1 + nf * w2;
    cU += pf * w2 + nf * w1;
  }
  *(f16x8*)(Ab + (size_t)m * KS + k) = h;
  *(f16x8*)(Ab + (size_t)(D + m) * KS + k) = h;

  __shared__ float redL[4], redU[4];
#pragma unroll
  for (int off = 32; off > 0; off >>= 1) {
    cL += __shfl_down(cL, off);
    cU += __shfl_down(cU, off);
  }
  const int wave = tid >> 6, lane = tid & 63;
  if (lane == 0) { redL[wave] = cL; redU[wave] = cU; }
  __syncthreads();
  if (tid == 0) {
    float bL = b[m] + redL[0] + redL[1] + redL[2] + redL[3];
    float bU = b[m] + redU[0] + redU[1] + redU[2] + redU[3];
    blbu[m] = bL; blbu[D + m] = bU;
  }
}

// ---- standalone prep: Bsum/Bdif transposed panels (layer 7 bootstrap) ------
__global__ __launch_bounds__(512) void k_prep(
    const float* __restrict__ srcAl, const float* __restrict__ srcAu,
    f16* __restrict__ Bb) {
  const int p = blockIdx.x, tid = threadIdx.x;
  const size_t MS = (size_t)D * D;
  const int col = (p & 31) * 64 + (tid & 63);
  const int k0 = (p >> 5) * 64 + (tid >> 6) * 8;
  float sl[8], su[8];
#pragma unroll
  for (int j = 0; j < 8; ++j) {
    sl[j] = srcAl[(size_t)(k0 + j) * D + col];
    su[j] = srcAu[(size_t)(k0 + j) * D + col];
  }
  f16x8 hs, hd;
#pragma unroll
  for (int j = 0; j < 8; ++j) {
    hs[j] = (f16)((sl[j] + su[j]) * 0.5f);
    hd[j] = (f16)((sl[j] - su[j]) * 0.5f);
  }
  *(f16x8*)(Bb + (size_t)col * KS + k0) = hs;
  *(f16x8*)(Bb + MS + (size_t)col * KS + k0) = hd;
}

// ---- step GEMM: C = S·Bsum ± |S|·Bdif --------------------------------------
// R2/R8 skeleton: BK=64, 8 waves (4M x 2N, 64x64 each), all operands staged
// via gload_lds with the measured-zero-conflict chunk^=(row&7) swizzle.
// Signed state: 64 MFMA per wave per tile (2 k-slices x (16 sum + 16 dif)).
// Double buffer (128 KiB); stage(t+1) issued at tile start -> vmcnt(0) at
// tile end has ~2500 cyc of MFMA cover. In-loop transpose rides one tile.
__global__ __launch_bounds__(512, 1) void k_gemm(
    const f16* __restrict__ A,     // [2D][KS] signed state
    const f16* __restrict__ Bb,    // [2][D][KS] Bsum,Bdif (transposed)
    f16* __restrict__ BTn,         // next layer's B buffer
    const float* __restrict__ nAl, const float* __restrict__ nAu,
    const float* __restrict__ w1, const float* __restrict__ w2,
    float* __restrict__ bdst,      // blbu (t<7) or outacc (t=7)
    f16* __restrict__ An,          // [2D][KS] next state
    const int do_tr, const int wstate) {
  __shared__ __align__(16) f16 lds[2 * BUFSZ];   // 128 KiB double buffer
  const size_t MS = (size_t)D * D;

  // bijective XCD swizzle over the 16x16 tile grid
  const int flat = blockIdx.x;
  const int xcd = flat & 7, idx = flat >> 3;
  const int by = (xcd >> 1) * 4 + (idx >> 3);
  const int bx = (xcd & 1) * 8 + (idx & 7);
  const int m0 = by * BM;
  const int n0 = bx * BN;

  const int tid = threadIdx.x;
  const int wave = tid >> 6, lane = tid & 63;
  const int wm = (wave & 3) * 64, wn = (wave >> 2) * 64;
  const int lr = lane & 15, lq = lane >> 4;
  const int sub = lane >> 3;                 // staging row within 8-row region
  const int cg = ((lane & 7) ^ sub) * 8;     // inverse-swizzled src chunk
  const int low = (m0 < D) ? 1 : 0;
  const unsigned amask = low ? 0x7FFF7FFFu : 0xFFFFFFFFu;  // |S| or -|S|
  const unsigned omask = low ? 0x00000000u : 0x80008000u;
  const f16* Bs = Bb;
  const f16* Bd = Bb + MS;

  f32x4 acc[4][4];
#pragma unroll
  for (int m = 0; m < 4; ++m)
#pragma unroll
    for (int n = 0; n < 4; ++n)
      acc[m][n] = (f32x4){0.f, 0.f, 0.f, 0.f};

  // stage one K-tile: 8 gload16/thread (A: 4 regions, Bsum: 2, Bdif: 2)
  auto stage = [&](int kt, int buf) {
    f16* bA = lds + buf * BUFSZ;
    f16* bB = bA + AROWS * BK;
    const size_t gk = (size_t)kt * BK;
#pragma unroll
    for (int i = 0; i < 4; ++i) {
      const int r = i * 8 + wave;            // A regions 0..31
      gload16(A + (size_t)(m0 + r * 8 + sub) * KS + gk + cg, bA + r * 512);
    }
#pragma unroll
    for (int i = 0; i < 2; ++i) {
      const int r = i * 8 + wave;            // Bsum regions 0..15 -> rows 0..127
      gload16(Bs + (size_t)(n0 + r * 8 + sub) * KS + gk + cg, bB + r * 512);
    }
#pragma unroll
    for (int i = 0; i < 2; ++i) {
      const int r = i * 8 + wave;            // Bdif regions -> rows 128..255
      gload16(Bd + (size_t)(n0 + r * 8 + sub) * KS + gk + cg,
              bB + (16 + r) * 512);
    }
  };

  // prologue: stage tile 0, drain, barrier
  stage(0, 0);
  asm volatile("s_waitcnt vmcnt(0)" ::: "memory");
  __builtin_amdgcn_sched_barrier(0);
  __builtin_amdgcn_s_barrier();
  __builtin_amdgcn_sched_barrier(0);

  float trl[8], tru[8];   // in-flight transpose column (static indexing)

  for (int t = 0; t < NT; ++t) {
    const f16* bA = lds + (t & 1) * BUFSZ;
    const f16* bB = bA + AROWS * BK;
    const int tmod = t & 7;

    if (do_tr && tmod == 4) {    // store panel loaded at t-2 (vmcnt(0)-drained)
      const int p = flat * 4 + (t >> 3);
      const int col = (p & 31) * 64 + (tid & 63);
      const int k0 = (p >> 5) * 64 + (tid >> 6) * 8;
      f16x8 hs, hd;
#pragma unroll
      for (int j = 0; j < 8; ++j) {
        hs[j] = (f16)((trl[j] + tru[j]) * 0.5f);
        hd[j] = (f16)((trl[j] - tru[j]) * 0.5f);
      }
      *(f16x8*)(BTn + (size_t)col * KS + k0) = hs;
      *(f16x8*)(BTn + MS + (size_t)col * KS + k0) = hd;
    }
    if (do_tr && tmod == 2) {    // issue 16 f32 column loads for panel
      const int p = flat * 4 + (t >> 3);
      const int col = (p & 31) * 64 + (tid & 63);
      const int k0 = (p >> 5) * 64 + (tid >> 6) * 8;
#pragma unroll
      for (int j = 0; j < 8; ++j) {
        trl[j] = nAl[(size_t)(k0 + j) * D + col];
        tru[j] = nAu[(size_t)(k0 + j) * D + col];
      }
    }
    __builtin_amdgcn_sched_barrier(0);   // pin VMEM issue order

    if (t + 1 < NT) stage(t + 1, (t + 1) & 1);   // prefetch next tile

#pragma unroll
    for (int ks = 0; ks < 2; ++ks) {
      f16x8 a[4], bs4[4], bd4[4];
#pragma unroll
      for (int m = 0; m < 4; ++m)
        a[m] = *(const f16x8*)(bA + (wm + m * 16 + lr) * BK
                               + ((ks * 4 + lq) ^ (lane & 7)) * 8);
#pragma unroll
      for (int n = 0; n < 4; ++n) {
        const int ch = ((ks * 4 + lq) ^ (lane & 7)) * 8;
        bs4[n] = *(const f16x8*)(bB + (wn + n * 16 + lr) * BK + ch);
        bd4[n] = *(const f16x8*)(bB + (128 + wn + n * 16 + lr) * BK + ch);
      }
      __builtin_amdgcn_s_setprio(1);
#pragma unroll
      for (int m = 0; m < 4; ++m)
#pragma unroll
        for (int n = 0; n < 4; ++n)
          acc[m][n] = __builtin_amdgcn_mfma_f32_16x16x32_f16(
              bs4[n], a[m], acc[m][n], 0, 0, 0);
      f16x8 ax[4];
#pragma unroll
      for (int m = 0; m < 4; ++m) {       // |S| (lower) or -|S| (upper)
        u32x4 u = *(const u32x4*)&a[m];
        u = (u & amask) | omask;
        ax[m] = *(const f16x8*)&u;
      }
#pragma unroll
      for (int m = 0; m < 4; ++m)
#pragma unroll
        for (int n = 0; n < 4; ++n)
          acc[m][n] = __builtin_amdgcn_mfma_f32_16x16x32_f16(
              bd4[n], ax[m], acc[m][n], 0, 0, 0);
      __builtin_amdgcn_s_setprio(0);
    }

    asm volatile("s_waitcnt vmcnt(0)" ::: "memory");   // next tile landed
    __builtin_amdgcn_sched_barrier(0);
    __builtin_amdgcn_s_barrier();
    __builtin_amdgcn_sched_barrier(0);
  }

  // ---- epilogue: signed state store + fused bias contribution ----
  f32x4 w1v[4], w2v[4];
#pragma unroll
  for (int n = 0; n < 4; ++n) {
    const int col = n0 + wn + n * 16 + lq * 4;
    w1v[n] = *(const f32x4*)(w1 + col);
    w2v[n] = *(const f32x4*)(w2 + col);
  }
  float rowsum[4] = {0.f, 0.f, 0.f, 0.f};
#pragma unroll
  for (int m = 0; m < 4; ++m) {
#pragma unroll
    for (int n = 0; n < 4; ++n) {
      const size_t row = (size_t)(m0 + wm + m * 16 + lr);
      const int col = n0 + wn + n * 16 + lq * 4;
      f16x4 h;
#pragma unroll
      for (int r = 0; r < 4; ++r) {
        float v = acc[m][n][r];
        float pf = fmaxf(v, 0.f), qf = fminf(v, 0.f);
        h[r] = (f16)v;
        float wa = low ? w1v[n][r] : w2v[n][r];
        float wb = low ? w2v[n][r] : w1v[n][r];
        rowsum[m] += pf * wa + qf * wb;
      }
      if (wstate)
        *(f16x4*)(An + row * KS + col) = h;
    }
  }
#pragma unroll
  for (int m = 0; m < 4; ++m) {
    float v = rowsum[m];
    v += __shfl_down(v, 32);
    v += __shfl_down(v, 16);
    if (lane < 16)
      atomicAdd(bdst + m0 + wm + m * 16 + lane, v);
  }
}

// ---- final: out[R] = outacc[R] + blbu[R] -----------------------------------
__global__ __launch_bounds__(256) void k_final(
    const float* __restrict__ outacc, const float* __restrict__ blbu,
    float* __restrict__ out) {
  const int R = blockIdx.x * 256 + threadIdx.x;
  out[R] = outacc[R] + blbu[R];
}

// ---- host ------------------------------------------------------------------
extern "C" void kernel_launch(void* const* d_in, const int* in_sizes, int n_in,
                              void* d_out, int out_size, void* d_ws, size_t ws_size,
                              hipStream_t stream) {
  (void)in_sizes; (void)n_in; (void)out_size;
  const float* A   = (const float*)d_in[0];
  const float* b   = (const float*)d_in[1];
  const float* hAl = (const float*)d_in[2];
  const float* hAu = (const float*)d_in[3];
  const float* hbl = (const float*)d_in[4];
  const float* hbu = (const float*)d_in[5];
  const float* lo  = (const float*)d_in[6];
  const float* up  = (const float*)d_in[7];
  float* out = (float*)d_out;

  const size_t AS = (size_t)2 * D * KS;     // signed state elems (f16)
  const size_t BS = (size_t)2 * D * D;      // Bsum+Bdif elems (f16)
  const size_t MS = (size_t)D * D;
  char* base = (char*)d_ws;
  f16* Ab0   = (f16*)base;
  f16* Ab1   = Ab0 + AS;
  f16* Bb0   = Ab1 + AS;
  float* blbu   = (float*)(Bb0 + BS);
  float* outacc = blbu + 2 * D;
  f16* Bb1   = (f16*)(outacc + 2 * D);
  const size_t need_fused = (size_t)((char*)(Bb1 + BS) - base);
  const bool fused = ws_size >= need_fused;

  k_init<<<dim3(D), 256, 0, stream>>>(
      A, b, hbl + (size_t)7 * D, hbu + (size_t)7 * D, Ab0, blbu, outacc);
  k_prep<<<dim3(1024), 512, 0, stream>>>(          // layer 7 -> Bb0
      hAl + (size_t)7 * MS, hAu + (size_t)7 * MS, Bb0);

  f16* cur = Ab0;
  f16* nxt = Ab1;
  for (int t = 0; t < L; ++t) {
    const int nlayer = 6 - t;   // layer for step t+1 (bias weights + transpose)
    const float* w1 = (t < 7) ? hbl + (size_t)nlayer * D : lo;
    const float* w2 = (t < 7) ? hbu + (size_t)nlayer * D : up;
    float* bd = (t < 7) ? blbu : outacc;
    f16* BT  = (fused && (t & 1)) ? Bb1 : Bb0;
    f16* BTn = fused ? ((t & 1) ? Bb0 : Bb1) : Bb0;
    const float* nl = (t < 7) ? hAl + (size_t)nlayer * MS : hAl;
    const float* nu = (t < 7) ? hAu + (size_t)nlayer * MS : hAu;
    if (!fused && t > 0)
      k_prep<<<dim3(1024), 512, 0, stream>>>(
          hAl + (size_t)(7 - t) * MS, hAu + (size_t)(7 - t) * MS, Bb0);
    const int do_tr = (fused && t < 7) ? 1 : 0;
    const int wstate = (t < 7) ? 1 : 0;
    k_gemm<<<dim3(256), 512, 0, stream>>>(cur, BT, BTn, nl, nu, w1, w2, bd,
                                          nxt, do_tr, wstate);
    f16* tmp = cur; cur = nxt; nxt = tmp;
  }
  k_final<<<dim3(2 * D / 256), 256, 0, stream>>>(outacc, blbu, out);
}